// Round 14
// baseline (182.042 us; speedup 1.0000x reference)
//
#include <hip/hip_runtime.h>

typedef short short8 __attribute__((ext_vector_type(8)));
typedef float f32x4 __attribute__((ext_vector_type(4)));
typedef unsigned short u16;
typedef unsigned short u16x4 __attribute__((ext_vector_type(4)));
typedef unsigned short u16x8 __attribute__((ext_vector_type(8)));

#define L_SEQ 4096
#define NHEAD 16
#define HDIM  64
#define DMODEL 1024
#define N3    3072
#define HL    (L_SEQ * HDIM)

__device__ __forceinline__ u16 f2bf(float f) {
  union { float f; unsigned u; } v; v.f = f;
  return (u16)((v.u + 0x7fffu + ((v.u >> 16) & 1u)) >> 16);
}

__device__ __forceinline__ unsigned cvt_pk_bf16(float lo, float hi) {
  unsigned r;
  asm("v_cvt_pk_bf16_f32 %0, %1, %2" : "=v"(r) : "v"(lo), "v"(hi));
  return r;
}

__device__ __forceinline__ void gl2lds16(const void* g, void* l) {
  __builtin_amdgcn_global_load_lds(
      (const __attribute__((address_space(1))) unsigned int*)g,
      (__attribute__((address_space(3))) unsigned int*)l, 16, 0, 0);
}

__device__ __forceinline__ float fexp2(float x) { return __builtin_amdgcn_exp2f(x); }

// ------- fused convert: x f32->bf16 (blocks 0..2047) ; W cvt+transpose (2048..2815) -------
__global__ void cvt_fused_kernel(const float* __restrict__ x, u16* __restrict__ xb,
                                 const float* __restrict__ W, u16* __restrict__ Wt) {
  if (blockIdx.x < 2048) {
    int i = blockIdx.x * blockDim.x + threadIdx.x;
    const f32x4* p = (const f32x4*)x + (size_t)i * 2;
    f32x4 a = p[0], b = p[1];
    u16x8 o;
    o[0] = f2bf(a[0]); o[1] = f2bf(a[1]); o[2] = f2bf(a[2]); o[3] = f2bf(a[3]);
    o[4] = f2bf(b[0]); o[5] = f2bf(b[1]); o[6] = f2bf(b[2]); o[7] = f2bf(b[3]);
    ((u16x8*)xb)[i] = o;
  } else {
    __shared__ float t[64][65];
    int idx = blockIdx.x - 2048;
    int k0 = (idx & 15) * 64, n0 = (idx >> 4) * 64;
    int tr = threadIdx.x >> 4;
    int tc = (threadIdx.x & 15) * 4;
    for (int rr = tr; rr < 64; rr += 16) {
      f32x4 v = *(const f32x4*)&W[(size_t)(k0 + rr) * N3 + n0 + tc];
      t[rr][tc] = v[0]; t[rr][tc + 1] = v[1]; t[rr][tc + 2] = v[2]; t[rr][tc + 3] = v[3];
    }
    __syncthreads();
    for (int rr = tr; rr < 64; rr += 16) {
      u16x4 o;
      o[0] = f2bf(t[tc + 0][rr]); o[1] = f2bf(t[tc + 1][rr]);
      o[2] = f2bf(t[tc + 2][rr]); o[3] = f2bf(t[tc + 3][rr]);
      *(u16x4*)&Wt[(size_t)(n0 + rr) * DMODEL + k0 + tc] = o;
    }
  }
}

// ---------------- QKV GEMM + bias + RoPE epilogue (proven, XCD swizzle) ----------------
#define GBM 128
#define GBN 128
#define GBK 64

__global__ __launch_bounds__(256, 2) void gemm_qkv_kernel(
    const u16* __restrict__ xb, const u16* __restrict__ wt,
    const float* __restrict__ bias, const float* __restrict__ freqs,
    u16* __restrict__ Qb, u16* __restrict__ Kb, u16* __restrict__ Vt) {
  __shared__ u16 Asm[GBM * GBK];
  __shared__ u16 Bsm[GBN * GBK];
  const int tid = threadIdx.x, lane = tid & 63, wid = tid >> 6;
  const int lr = lane & 15, lh = lane >> 4;
  const int swz = (blockIdx.x % 8) * 96 + blockIdx.x / 8;
  const int bx = swz % (N3 / GBN), by = swz / (N3 / GBN);
  const int m0 = by * GBM, n0 = bx * GBN;
  const int wr = wid >> 1, wc = wid & 1;
  const char* xbB = (const char*)xb;
  const char* wtB = (const char*)wt;
  char* AsmB = (char*)Asm;
  char* BsmB = (char*)Bsm;

  int pbase[4]; size_t srcAoff[4], srcBoff[4];
#pragma unroll
  for (int i = 0; i < 4; i++) {
    int p = wid * 4096 + i * 1024 + lane * 16;
    int row = p >> 7, slot = (p & 127) >> 4;
    int sw = (slot ^ (row & 7)) * 16;
    pbase[i] = p;
    srcAoff[i] = (size_t)(m0 + row) * (DMODEL * 2) + sw;
    srcBoff[i] = (size_t)(n0 + row) * (DMODEL * 2) + sw;
  }

  int aoff[4][2], boff[4][2];
#pragma unroll
  for (int mi = 0; mi < 4; mi++) {
    int row = wr * 64 + mi * 16 + lr;
#pragma unroll
    for (int kc = 0; kc < 2; kc++)
      aoff[mi][kc] = row * 128 + ((kc * 64 + lh * 16) ^ ((row & 7) << 4));
  }
#pragma unroll
  for (int ni = 0; ni < 4; ni++) {
    int row = wc * 64 + ni * 16 + lr;
#pragma unroll
    for (int kc = 0; kc < 2; kc++)
      boff[ni][kc] = row * 128 + ((kc * 64 + lh * 16) ^ ((row & 7) << 4));
  }

  f32x4 acc[4][4] = {};

  for (int k0 = 0; k0 < DMODEL; k0 += GBK) {
    __syncthreads();
#pragma unroll
    for (int i = 0; i < 4; i++) {
      gl2lds16(xbB + srcAoff[i] + (size_t)k0 * 2, AsmB + pbase[i]);
      gl2lds16(wtB + srcBoff[i] + (size_t)k0 * 2, BsmB + pbase[i]);
    }
    __syncthreads();
#pragma unroll
    for (int kc = 0; kc < 2; kc++) {
      short8 a[4], b[4];
#pragma unroll
      for (int mi = 0; mi < 4; mi++) a[mi] = *(const short8*)(AsmB + aoff[mi][kc]);
#pragma unroll
      for (int ni = 0; ni < 4; ni++) b[ni] = *(const short8*)(BsmB + boff[ni][kc]);
#pragma unroll
      for (int mi = 0; mi < 4; mi++)
#pragma unroll
        for (int ni = 0; ni < 4; ni++)
          acc[mi][ni] = __builtin_amdgcn_mfma_f32_16x16x32_bf16(a[mi], b[ni], acc[mi][ni], 0, 0, 0);
    }
  }

  const float QSCALE = 0.125f * 1.44269504088896f;
  const int colbase = n0 + wc * 64;
#pragma unroll
  for (int ni = 0; ni < 4; ni++) {
    int col = colbase + ni * 16 + lr;
    float bv = bias[col];
    int sect = col >> 10;
    int cc = col & 1023;
    int h = cc >> 6, j = cc & 63;
#pragma unroll
    for (int mi = 0; mi < 4; mi++) {
      int row0 = m0 + wr * 64 + mi * 16 + lh * 4;
      float v[4];
#pragma unroll
      for (int r = 0; r < 4; r++) v[r] = acc[mi][ni][r] + bv;
      if (sect < 2) {
        int i2 = j >> 1;
        bool odd = (j & 1) != 0;
#pragma unroll
        for (int r = 0; r < 4; r++) {
          float pv = __shfl_xor(v[r], 1);
          float2 cs = *(const float2*)&freqs[((size_t)(row0 + r) * 32 + i2) * 2];
          v[r] = odd ? (v[r] * cs.x + pv * cs.y) : (v[r] * cs.x - pv * cs.y);
          if (sect == 0) v[r] *= QSCALE;
        }
        u16* dst = (sect == 0 ? Qb : Kb) + (size_t)h * HL + (size_t)row0 * HDIM + j;
#pragma unroll
        for (int r = 0; r < 4; r++) dst[(size_t)r * HDIM] = f2bf(v[r]);
      } else {
        u16x4 o;
#pragma unroll
        for (int r = 0; r < 4; r++) o[r] = f2bf(v[r]);
        *(u16x4*)&Vt[(size_t)h * HL + (size_t)j * L_SEQ + row0] = o;
      }
    }
  }
}

// ---- causal flash attention (v14: R10 two-pass body, V direct global->reg) ----
#define QBLK 64
#define KBLK 64
#define LD8(p) (*(const short8*)(p))

__global__ __launch_bounds__(256, 4) void flash_kernel(
    const u16* __restrict__ Qb, const u16* __restrict__ Kb,
    const u16* __restrict__ Vt, float* __restrict__ out) {
  __shared__ char Ksm[2][KBLK * 128];      // 16KB
  __shared__ char Psm[4][16 * 128];        // 8KB -> 24KB total
  const int tid = threadIdx.x, lane = tid & 63, wid = tid >> 6;
  const int lr = lane & 15, lh = lane >> 4;
  const int bid = blockIdx.x;
  const int h = bid & 15;
  const int pr = bid >> 4;                 // pair index 0..31
  const char* Qh = (const char*)(Qb + (size_t)h * HL);
  const char* Kh = (const char*)(Kb + (size_t)h * HL);
  const char* Vh = (const char*)(Vt + (size_t)h * HL);
  char* Pw = Psm[wid];

  // K staging: per wave 2 chunks of 1KB
  int pOff[2], KsrcOff[2];
#pragma unroll
  for (int i = 0; i < 2; i++) {
    int p = wid * 2048 + i * 1024 + lane * 16;
    int row = p >> 7, slot = (p & 127) >> 4;
    pOff[i] = p;
    KsrcOff[i] = row * 128 + ((slot ^ (row & 7)) << 4);
  }

  // V fragment global addresses: bv[vn][pc] <- Vh + (vn*16+lr)*L*2 + (kt+pc*32+lh*8)*2
  const size_t vbase = (size_t)lr * (L_SEQ * 2) + (size_t)lh * 16;

  // two q-tiles per block: long (63-pr) then short (pr) -> 65 tile-iters per block
  for (int pass = 0; pass < 2; ++pass) {
    const int qb = pass == 0 ? (63 - pr) : pr;
    const int q0 = qb * QBLK;
    const int wmin = q0 + wid * 16;
    const int qrow = wmin + lr;
    const int nt = qb + 1;

    short8 qa[2];
#pragma unroll
    for (int kc = 0; kc < 2; kc++)
      qa[kc] = LD8(Qh + (size_t)qrow * 128 + kc * 64 + lh * 16);

    f32x4 o[4] = {};
    float m_r = -__builtin_inff(), ls = 0.f;

    // prologue: stage K tile 0; load V tile 0 fragments to registers
#pragma unroll
    for (int i = 0; i < 2; i++)
      gl2lds16(Kh + KsrcOff[i], Ksm[0] + pOff[i]);
    short8 bv[4][2];
#pragma unroll
    for (int vn = 0; vn < 4; vn++)
#pragma unroll
      for (int pc = 0; pc < 2; pc++)
        bv[vn][pc] = LD8(Vh + vbase + (size_t)vn * 16 * (L_SEQ * 2) + (size_t)pc * 64);
    __syncthreads();

    for (int t = 0; t < nt; ++t) {
      const int kt = t * KBLK;
      const int cur = t & 1;
      if (t + 1 < nt) {
#pragma unroll
        for (int i = 0; i < 2; i++)
          gl2lds16(Kh + (size_t)(kt + KBLK) * 128 + KsrcOff[i], Ksm[cur ^ 1] + pOff[i]);
      }
      const char* Kc = Ksm[cur];

      // S^T = K Q^T : lane holds q-row = qrow (col), k = kt + ni*16 + lh*4 + r
      f32x4 sfr[4];
      __builtin_amdgcn_s_setprio(1);
#pragma unroll
      for (int ni = 0; ni < 4; ni++) {
        int row = ni * 16 + lr;
        short8 bk0 = LD8(Kc + row * 128 + ((lh * 16) ^ ((row & 7) << 4)));
        short8 bk1 = LD8(Kc + row * 128 + ((64 + lh * 16) ^ ((row & 7) << 4)));
        f32x4 z = {};
        z = __builtin_amdgcn_mfma_f32_16x16x32_bf16(bk0, qa[0], z, 0, 0, 0);
        z = __builtin_amdgcn_mfma_f32_16x16x32_bf16(bk1, qa[1], z, 0, 0, 0);
        sfr[ni] = z;
      }
      __builtin_amdgcn_s_setprio(0);

      // causal mask: only the diagonal tile needs it
      if (kt + KBLK - 1 > wmin) {
#pragma unroll
        for (int ni = 0; ni < 4; ni++)
#pragma unroll
          for (int r = 0; r < 4; r++)
            if (kt + ni * 16 + lh * 4 + r > qrow) sfr[ni][r] = -__builtin_inff();
      }

      // row max: lane-local 16 then reduce over lh group
      float pmax = sfr[0][0];
#pragma unroll
      for (int ni = 0; ni < 4; ni++)
#pragma unroll
        for (int r = 0; r < 4; r++) pmax = fmaxf(pmax, sfr[ni][r]);
      pmax = fmaxf(pmax, __shfl_xor(pmax, 16));
      pmax = fmaxf(pmax, __shfl_xor(pmax, 32));

      // defer-rescale (T13): only when max grew by > 8 (exp2-domain)
      if (__any(pmax > m_r + 8.f)) {
        float mn = fmaxf(m_r, pmax);
        float alpha = fexp2(m_r - mn);
        m_r = mn;
        ls *= alpha;
        float ao[4];
#pragma unroll
        for (int r = 0; r < 4; r++) ao[r] = __shfl(alpha, (lane & 48) | (lh * 4 + r));
#pragma unroll
        for (int vn = 0; vn < 4; vn++)
#pragma unroll
          for (int r = 0; r < 4; r++) o[vn][r] *= ao[r];
      }

      // P = exp2(s - m), pack to bf16 pairs, partial row-sum
      float psum = 0.f;
      unsigned Wp[4][2];
#pragma unroll
      for (int ni = 0; ni < 4; ni++) {
        float p0 = fexp2(sfr[ni][0] - m_r);
        float p1 = fexp2(sfr[ni][1] - m_r);
        float p2 = fexp2(sfr[ni][2] - m_r);
        float p3 = fexp2(sfr[ni][3] - m_r);
        psum += (p0 + p1) + (p2 + p3);
        Wp[ni][0] = cvt_pk_bf16(p0, p1);
        Wp[ni][1] = cvt_pk_bf16(p2, p3);
      }
      ls += psum;

      // store P^T -> Psm as [q=lr][k] bf16, XOR-swizzled by q-row
#pragma unroll
      for (int ni = 0; ni < 4; ni++) {
        uint2 w2; w2.x = Wp[ni][0]; w2.y = Wp[ni][1];
        *(uint2*)(Pw + lr * 128 + ((ni * 32 + lh * 8) ^ ((lr & 7) << 4))) = w2;
      }
      asm volatile("s_waitcnt lgkmcnt(0)" ::: "memory");

      // O += P V (V fragments already in registers)
      __builtin_amdgcn_s_setprio(1);
#pragma unroll
      for (int pc = 0; pc < 2; pc++) {
        short8 pa = LD8(Pw + lr * 128 + ((pc * 64 + lh * 16) ^ ((lr & 7) << 4)));
#pragma unroll
        for (int vn = 0; vn < 4; vn++)
          o[vn] = __builtin_amdgcn_mfma_f32_16x16x32_bf16(pa, bv[vn][pc], o[vn], 0, 0, 0);
      }
      __builtin_amdgcn_s_setprio(0);

      // prefetch next V tile fragments (L2 latency hides under next QK^T+softmax)
      if (t + 1 < nt) {
        const size_t kn2 = (size_t)(kt + KBLK) * 2;
#pragma unroll
        for (int vn = 0; vn < 4; vn++)
#pragma unroll
          for (int pc = 0; pc < 2; pc++)
            bv[vn][pc] = LD8(Vh + vbase + (size_t)vn * 16 * (L_SEQ * 2) + kn2 + (size_t)pc * 64);
      }

      __syncthreads();
    }

    // epilogue: full row-sum, normalize, write f32 out [L][1024] (no LDS)
    ls += __shfl_xor(ls, 16);
    ls += __shfl_xor(ls, 32);
    float inv = 1.0f / ls;
    float invo[4];
#pragma unroll
    for (int r = 0; r < 4; r++) invo[r] = __shfl(inv, (lane & 48) | (lh * 4 + r));
#pragma unroll
    for (int r = 0; r < 4; r++) {
      int rowv = wmin + lh * 4 + r;
      float* op = out + (size_t)rowv * DMODEL + h * HDIM;
#pragma unroll
      for (int vn = 0; vn < 4; vn++) op[vn * 16 + lr] = o[vn][r] * invo[r];
    }
  }
}

extern "C" void kernel_launch(void* const* d_in, const int* in_sizes, int n_in,
                              void* d_out, int out_size, void* d_ws, size_t ws_size,
                              hipStream_t stream) {
  const float* x = (const float*)d_in[0];
  const float* freqs = (const float*)d_in[1];
  const float* W = (const float*)d_in[2];
  const float* bias = (const float*)d_in[3];
  float* out = (float*)d_out;

  char* ws = (char*)d_ws;
  u16* xb = (u16*)ws;
  u16* wt = (u16*)(ws + 8u * 1024 * 1024);
  u16* Qb = (u16*)(ws + 14u * 1024 * 1024);
  u16* Kb = (u16*)(ws + 22u * 1024 * 1024);
  u16* Vt = (u16*)(ws + 30u * 1024 * 1024);

  cvt_fused_kernel<<<2816, 256, 0, stream>>>(x, xb, W, wt);
  gemm_qkv_kernel<<<768, 256, 0, stream>>>(xb, wt, bias, freqs, Qb, Kb, Vt);
  flash_kernel<<<512, 256, 0, stream>>>(Qb, Kb, Vt, out);
}

// Round 15
// 129.029 us; speedup vs baseline: 1.4109x; 1.4109x over previous
//
#include <hip/hip_runtime.h>

typedef short short8 __attribute__((ext_vector_type(8)));
typedef float f32x4 __attribute__((ext_vector_type(4)));
typedef unsigned short u16;
typedef unsigned short u16x4 __attribute__((ext_vector_type(4)));
typedef unsigned short u16x8 __attribute__((ext_vector_type(8)));

#define L_SEQ 4096
#define NHEAD 16
#define HDIM  64
#define DMODEL 1024
#define N3    3072
#define HL    (L_SEQ * HDIM)

__device__ __forceinline__ u16 f2bf(float f) {
  union { float f; unsigned u; } v; v.f = f;
  return (u16)((v.u + 0x7fffu + ((v.u >> 16) & 1u)) >> 16);
}

__device__ __forceinline__ unsigned cvt_pk_bf16(float lo, float hi) {
  unsigned r;
  asm("v_cvt_pk_bf16_f32 %0, %1, %2" : "=v"(r) : "v"(lo), "v"(hi));
  return r;
}

__device__ __forceinline__ void gl2lds16(const void* g, void* l) {
  __builtin_amdgcn_global_load_lds(
      (const __attribute__((address_space(1))) unsigned int*)g,
      (__attribute__((address_space(3))) unsigned int*)l, 16, 0, 0);
}

__device__ __forceinline__ float fexp2(float x) { return __builtin_amdgcn_exp2f(x); }

// ------- fused convert: x f32->bf16 (blocks 0..2047) ; W cvt+transpose (2048..2815) -------
__global__ void cvt_fused_kernel(const float* __restrict__ x, u16* __restrict__ xb,
                                 const float* __restrict__ W, u16* __restrict__ Wt) {
  if (blockIdx.x < 2048) {
    int i = blockIdx.x * blockDim.x + threadIdx.x;
    const f32x4* p = (const f32x4*)x + (size_t)i * 2;
    f32x4 a = p[0], b = p[1];
    u16x8 o;
    o[0] = f2bf(a[0]); o[1] = f2bf(a[1]); o[2] = f2bf(a[2]); o[3] = f2bf(a[3]);
    o[4] = f2bf(b[0]); o[5] = f2bf(b[1]); o[6] = f2bf(b[2]); o[7] = f2bf(b[3]);
    ((u16x8*)xb)[i] = o;
  } else {
    __shared__ float t[64][65];
    int idx = blockIdx.x - 2048;
    int k0 = (idx & 15) * 64, n0 = (idx >> 4) * 64;
    int tr = threadIdx.x >> 4;
    int tc = (threadIdx.x & 15) * 4;
    for (int rr = tr; rr < 64; rr += 16) {
      f32x4 v = *(const f32x4*)&W[(size_t)(k0 + rr) * N3 + n0 + tc];
      t[rr][tc] = v[0]; t[rr][tc + 1] = v[1]; t[rr][tc + 2] = v[2]; t[rr][tc + 3] = v[3];
    }
    __syncthreads();
    for (int rr = tr; rr < 64; rr += 16) {
      u16x4 o;
      o[0] = f2bf(t[tc + 0][rr]); o[1] = f2bf(t[tc + 1][rr]);
      o[2] = f2bf(t[tc + 2][rr]); o[3] = f2bf(t[tc + 3][rr]);
      *(u16x4*)&Wt[(size_t)(n0 + rr) * DMODEL + k0 + tc] = o;
    }
  }
}

// ---------------- QKV GEMM + bias + RoPE epilogue (3 blocks/CU: all 768 resident) ----------------
#define GBM 128
#define GBN 128
#define GBK 64

__global__ __launch_bounds__(256, 3) void gemm_qkv_kernel(
    const u16* __restrict__ xb, const u16* __restrict__ wt,
    const float* __restrict__ bias, const float* __restrict__ freqs,
    u16* __restrict__ Qb, u16* __restrict__ Kb, u16* __restrict__ Vt) {
  __shared__ u16 Asm[GBM * GBK];
  __shared__ u16 Bsm[GBN * GBK];
  const int tid = threadIdx.x, lane = tid & 63, wid = tid >> 6;
  const int lr = lane & 15, lh = lane >> 4;
  const int swz = (blockIdx.x % 8) * 96 + blockIdx.x / 8;
  const int bx = swz % (N3 / GBN), by = swz / (N3 / GBN);
  const int m0 = by * GBM, n0 = bx * GBN;
  const int wr = wid >> 1, wc = wid & 1;
  const char* xbB = (const char*)xb;
  const char* wtB = (const char*)wt;
  char* AsmB = (char*)Asm;
  char* BsmB = (char*)Bsm;

  int pbase[4]; size_t srcAoff[4], srcBoff[4];
#pragma unroll
  for (int i = 0; i < 4; i++) {
    int p = wid * 4096 + i * 1024 + lane * 16;
    int row = p >> 7, slot = (p & 127) >> 4;
    int sw = (slot ^ (row & 7)) * 16;
    pbase[i] = p;
    srcAoff[i] = (size_t)(m0 + row) * (DMODEL * 2) + sw;
    srcBoff[i] = (size_t)(n0 + row) * (DMODEL * 2) + sw;
  }

  int aoff[4][2], boff[4][2];
#pragma unroll
  for (int mi = 0; mi < 4; mi++) {
    int row = wr * 64 + mi * 16 + lr;
#pragma unroll
    for (int kc = 0; kc < 2; kc++)
      aoff[mi][kc] = row * 128 + ((kc * 64 + lh * 16) ^ ((row & 7) << 4));
  }
#pragma unroll
  for (int ni = 0; ni < 4; ni++) {
    int row = wc * 64 + ni * 16 + lr;
#pragma unroll
    for (int kc = 0; kc < 2; kc++)
      boff[ni][kc] = row * 128 + ((kc * 64 + lh * 16) ^ ((row & 7) << 4));
  }

  f32x4 acc[4][4] = {};

  for (int k0 = 0; k0 < DMODEL; k0 += GBK) {
    __syncthreads();
#pragma unroll
    for (int i = 0; i < 4; i++) {
      gl2lds16(xbB + srcAoff[i] + (size_t)k0 * 2, AsmB + pbase[i]);
      gl2lds16(wtB + srcBoff[i] + (size_t)k0 * 2, BsmB + pbase[i]);
    }
    __syncthreads();
#pragma unroll
    for (int kc = 0; kc < 2; kc++) {
      short8 a[4], b[4];
#pragma unroll
      for (int mi = 0; mi < 4; mi++) a[mi] = *(const short8*)(AsmB + aoff[mi][kc]);
#pragma unroll
      for (int ni = 0; ni < 4; ni++) b[ni] = *(const short8*)(BsmB + boff[ni][kc]);
#pragma unroll
      for (int mi = 0; mi < 4; mi++)
#pragma unroll
        for (int ni = 0; ni < 4; ni++)
          acc[mi][ni] = __builtin_amdgcn_mfma_f32_16x16x32_bf16(a[mi], b[ni], acc[mi][ni], 0, 0, 0);
    }
  }

  const float QSCALE = 0.125f * 1.44269504088896f;
  const int colbase = n0 + wc * 64;
#pragma unroll
  for (int ni = 0; ni < 4; ni++) {
    int col = colbase + ni * 16 + lr;
    float bv = bias[col];
    int sect = col >> 10;
    int cc = col & 1023;
    int h = cc >> 6, j = cc & 63;
#pragma unroll
    for (int mi = 0; mi < 4; mi++) {
      int row0 = m0 + wr * 64 + mi * 16 + lh * 4;
      float v[4];
#pragma unroll
      for (int r = 0; r < 4; r++) v[r] = acc[mi][ni][r] + bv;
      if (sect < 2) {
        int i2 = j >> 1;
        bool odd = (j & 1) != 0;
#pragma unroll
        for (int r = 0; r < 4; r++) {
          float pv = __shfl_xor(v[r], 1);
          float2 cs = *(const float2*)&freqs[((size_t)(row0 + r) * 32 + i2) * 2];
          v[r] = odd ? (v[r] * cs.x + pv * cs.y) : (v[r] * cs.x - pv * cs.y);
          if (sect == 0) v[r] *= QSCALE;
        }
        u16* dst = (sect == 0 ? Qb : Kb) + (size_t)h * HL + (size_t)row0 * HDIM + j;
#pragma unroll
        for (int r = 0; r < 4; r++) dst[(size_t)r * HDIM] = f2bf(v[r]);
      } else {
        u16x4 o;
#pragma unroll
        for (int r = 0; r < 4; r++) o[r] = f2bf(v[r]);
        *(u16x4*)&Vt[(size_t)h * HL + (size_t)j * L_SEQ + row0] = o;
      }
    }
  }
}

// -------- causal flash attention (R10 proven: two-pass uniform pairing, 84.4us) --------
#define QBLK 64
#define KBLK 64

__global__ __launch_bounds__(256, 4) void flash_kernel(
    const u16* __restrict__ Qb, const u16* __restrict__ Kb,
    const u16* __restrict__ Vt, float* __restrict__ out) {
  __shared__ char Ksm[2][KBLK * 128];
  __shared__ char Vsm[2][HDIM * KBLK * 2];
  __shared__ char Psm[4][16 * 128];
  const int tid = threadIdx.x, lane = tid & 63, wid = tid >> 6;
  const int lr = lane & 15, lh = lane >> 4;
  const int bid = blockIdx.x;
  const int h = bid & 15;
  const int pr = bid >> 4;                 // pair index 0..31
  const char* Qh = (const char*)(Qb + (size_t)h * HL);
  const char* Kh = (const char*)(Kb + (size_t)h * HL);
  const char* Vh = (const char*)(Vt + (size_t)h * HL);
  char* Pw = Psm[wid];

  int pOff[2], KsrcOff[2], VsrcOff[2];
#pragma unroll
  for (int i = 0; i < 2; i++) {
    int p = wid * 2048 + i * 1024 + lane * 16;
    int row = p >> 7, slot = (p & 127) >> 4;
    int sw = (slot ^ (row & 7)) << 4;
    pOff[i] = p;
    KsrcOff[i] = row * 128 + sw;
    VsrcOff[i] = row * (L_SEQ * 2) + sw;
  }

  // two q-tiles per block: long (63-pr) then short (pr) -> 65 tile-iters for every block
  for (int pass = 0; pass < 2; ++pass) {
    const int qb = pass == 0 ? (63 - pr) : pr;
    const int q0 = qb * QBLK;
    const int wmin = q0 + wid * 16;
    const int qrow = wmin + lr;
    const int nt = qb + 1;

    short8 qa[2];
    {
      int row = q0 + wid * 16 + lr;
#pragma unroll
      for (int kc = 0; kc < 2; kc++)
        qa[kc] = *(const short8*)(Qh + (size_t)row * 128 + kc * 64 + lh * 16);
    }

    f32x4 o[4] = {};
    float m_r = -__builtin_inff(), ls = 0.f;

#pragma unroll
    for (int i = 0; i < 2; i++) {
      gl2lds16(Kh + KsrcOff[i], Ksm[0] + pOff[i]);
      gl2lds16(Vh + VsrcOff[i], Vsm[0] + pOff[i]);
    }
    __syncthreads();

    for (int t = 0; t < nt; ++t) {
      const int kt = t * KBLK;
      const int cur = t & 1;
      if (t + 1 < nt) {
        const size_t kn128 = (size_t)(kt + KBLK) * 128;
        const size_t kn2 = (size_t)(kt + KBLK) * 2;
#pragma unroll
        for (int i = 0; i < 2; i++) {
          gl2lds16(Kh + kn128 + KsrcOff[i], Ksm[cur ^ 1] + pOff[i]);
          gl2lds16(Vh + kn2 + VsrcOff[i], Vsm[cur ^ 1] + pOff[i]);
        }
      }
      const char* Kc = Ksm[cur];
      const char* Vc = Vsm[cur];

      f32x4 sfr[4];
      __builtin_amdgcn_s_setprio(1);
#pragma unroll
      for (int ni = 0; ni < 4; ni++) {
        int row = ni * 16 + lr;
        short8 bk0 = *(const short8*)(Kc + row * 128 + ((lh * 16) ^ ((row & 7) << 4)));
        short8 bk1 = *(const short8*)(Kc + row * 128 + ((64 + lh * 16) ^ ((row & 7) << 4)));
        f32x4 z = {};
        z = __builtin_amdgcn_mfma_f32_16x16x32_bf16(bk0, qa[0], z, 0, 0, 0);
        z = __builtin_amdgcn_mfma_f32_16x16x32_bf16(bk1, qa[1], z, 0, 0, 0);
        sfr[ni] = z;
      }
      __builtin_amdgcn_s_setprio(0);

      if (kt + KBLK - 1 > wmin) {
#pragma unroll
        for (int ni = 0; ni < 4; ni++)
#pragma unroll
          for (int r = 0; r < 4; r++)
            if (kt + ni * 16 + lh * 4 + r > qrow) sfr[ni][r] = -__builtin_inff();
      }

      float pmax = sfr[0][0];
#pragma unroll
      for (int ni = 0; ni < 4; ni++)
#pragma unroll
        for (int r = 0; r < 4; r++) pmax = fmaxf(pmax, sfr[ni][r]);
      pmax = fmaxf(pmax, __shfl_xor(pmax, 16));
      pmax = fmaxf(pmax, __shfl_xor(pmax, 32));

      if (__any(pmax > m_r + 8.f)) {
        float mn = fmaxf(m_r, pmax);
        float alpha = fexp2(m_r - mn);
        m_r = mn;
        ls *= alpha;
        float ao[4];
#pragma unroll
        for (int r = 0; r < 4; r++) ao[r] = __shfl(alpha, (lane & 48) | (lh * 4 + r));
#pragma unroll
        for (int vn = 0; vn < 4; vn++)
#pragma unroll
          for (int r = 0; r < 4; r++) o[vn][r] *= ao[r];
      }

      float psum = 0.f;
      unsigned Wp[4][2];
#pragma unroll
      for (int ni = 0; ni < 4; ni++) {
        float p0 = fexp2(sfr[ni][0] - m_r);
        float p1 = fexp2(sfr[ni][1] - m_r);
        float p2 = fexp2(sfr[ni][2] - m_r);
        float p3 = fexp2(sfr[ni][3] - m_r);
        psum += (p0 + p1) + (p2 + p3);
        Wp[ni][0] = cvt_pk_bf16(p0, p1);
        Wp[ni][1] = cvt_pk_bf16(p2, p3);
      }
      ls += psum;

#pragma unroll
      for (int ni = 0; ni < 4; ni++) {
        uint2 w2; w2.x = Wp[ni][0]; w2.y = Wp[ni][1];
        *(uint2*)(Pw + lr * 128 + ((ni * 32 + lh * 8) ^ ((lr & 7) << 4))) = w2;
      }
      asm volatile("s_waitcnt lgkmcnt(0)" ::: "memory");

      __builtin_amdgcn_s_setprio(1);
#pragma unroll
      for (int pc = 0; pc < 2; pc++) {
        short8 pa = *(const short8*)(Pw + lr * 128 + ((pc * 64 + lh * 16) ^ ((lr & 7) << 4)));
#pragma unroll
        for (int vn = 0; vn < 4; vn++) {
          int vrow = vn * 16 + lr;
          short8 bv = *(const short8*)(Vc + vrow * 128 + ((pc * 64 + lh * 16) ^ ((vrow & 7) << 4)));
          o[vn] = __builtin_amdgcn_mfma_f32_16x16x32_bf16(pa, bv, o[vn], 0, 0, 0);
        }
      }
      __builtin_amdgcn_s_setprio(0);

      __syncthreads();
    }

    ls += __shfl_xor(ls, 16);
    ls += __shfl_xor(ls, 32);
    float inv = 1.0f / ls;
    float invo[4];
#pragma unroll
    for (int r = 0; r < 4; r++) invo[r] = __shfl(inv, (lane & 48) | (lh * 4 + r));
#pragma unroll
    for (int r = 0; r < 4; r++) {
      int rowv = wmin + lh * 4 + r;
      float* op = out + (size_t)rowv * DMODEL + h * HDIM;
#pragma unroll
      for (int vn = 0; vn < 4; vn++) op[vn * 16 + lr] = o[vn][r] * invo[r];
    }
  }
}

extern "C" void kernel_launch(void* const* d_in, const int* in_sizes, int n_in,
                              void* d_out, int out_size, void* d_ws, size_t ws_size,
                              hipStream_t stream) {
  const float* x = (const float*)d_in[0];
  const float* freqs = (const float*)d_in[1];
  const float* W = (const float*)d_in[2];
  const float* bias = (const float*)d_in[3];
  float* out = (float*)d_out;

  char* ws = (char*)d_ws;
  u16* xb = (u16*)ws;
  u16* wt = (u16*)(ws + 8u * 1024 * 1024);
  u16* Qb = (u16*)(ws + 14u * 1024 * 1024);
  u16* Kb = (u16*)(ws + 22u * 1024 * 1024);
  u16* Vt = (u16*)(ws + 30u * 1024 * 1024);

  cvt_fused_kernel<<<2816, 256, 0, stream>>>(x, xb, W, wt);
  gemm_qkv_kernel<<<768, 256, 0, stream>>>(xb, wt, bias, freqs, Qb, Kb, Vt);
  flash_kernel<<<512, 256, 0, stream>>>(Qb, Kb, Vt, out);
}